// Round 1
// baseline (2494.201 us; speedup 1.0000x reference)
//
#include <hip/hip_runtime.h>
#include <math.h>

// Problem constants
#define Bn   8
#define Nn   64
#define Rn   2048
#define Dn   4096
#define Hn   512
#define NOc  151
#define NRc  51
#define Tt   3
#define BNt  (Bn*Nn)   // 512 objects
#define BRt  (Bn*Rn)   // 16384 relations
#define Mall (BRt+BNt) // 16896 = rel rows + appended obj rows

typedef __attribute__((ext_vector_type(8))) short short8;
typedef __attribute__((ext_vector_type(4))) float f32x4;

__device__ __forceinline__ float sigmf(float x){ return 1.0f/(1.0f+expf(-x)); }

__device__ __forceinline__ ushort f2bf_rne(float x){
  unsigned u = __float_as_uint(x);
  unsigned r = u + 0x7FFFu + ((u>>16)&1u);
  return (ushort)(r>>16);
}
__device__ __forceinline__ float bf2f(ushort h){
  return __uint_as_float(((unsigned)h)<<16);
}

// async global->LDS, 16B per lane; LDS dest = wave-uniform base + lane*16
__device__ __forceinline__ void async_ld16(const ushort* g, ushort* l){
  __builtin_amdgcn_global_load_lds(
      (const __attribute__((address_space(1))) unsigned int*)g,
      (__attribute__((address_space(3))) unsigned int*)l, 16, 0, 0);
}

// ---------------------------------------------------------------------------
// bf16x3 MFMA GEMM, v2 pipeline:
//  - LDS double-buffered (A and B), ONE barrier per 32-wide K-step.
//  - B staged via global_load_lds (linear dest); source address carries the
//    XOR chunk swizzle (c ^= (row>>1)&3) so swizzled reads are conflict-free.
//  - A reg-staged (fp32 split or plane copy), written to back buffer after
//    MFMA (counted vmcnt: A loads issued before B gloads).
//  - Next-tile loads issued at TOP of iter: pre-barrier vmcnt(0) drains loads
//    that had the full MFMA phase to land (T3-lite 2-phase).
// B pre-split bf16 hi/lo planes [N][ldb], k-padded AND row-padded to BN mult.
// C = Ah*Bh + Ah*Bl + Al*Bh, fp32 accumulate (~fp32 accuracy).
// swz: XCD-aware block swizzle (requires gridDim.y % 8 == 0).
// mode 0: out = act(acc (+Cin) (+bias)) -> fp32 C (dupoff) and/or planes.
// mode 1 (GATE): z=sig(acc_z+g+bz)->Zb ; r*h=sig(acc_r+g+br)*Hf -> RH planes.
// mode 2 (UPD):  hn=(1-z)h+z*tanh(acc+g+bh) -> Hf fp32 + HX h-planes.
// ---------------------------------------------------------------------------
template<int BM,int BN,int ASPLIT>
__global__ __launch_bounds__(256)
void gemm_b3(const float* __restrict__ Af,
             const ushort* __restrict__ Aph, const ushort* __restrict__ Apl,
             const ushort* __restrict__ Bhg, const ushort* __restrict__ Blg,
             float* __restrict__ Cf, const float* __restrict__ Cin,
             int M,int N,int K,int lda,int ldb,int ldc,
             const float* __restrict__ bias, const float* __restrict__ bias2,
             int act,int dupoff,
             ushort* __restrict__ Cph, ushort* __restrict__ Cpl,int ldcp,int dupp,
             int swz,int mode,const int* __restrict__ rel,
             const float* __restrict__ Gso,const float* __restrict__ G1,
             int brt,float* __restrict__ Zb,
             ushort* __restrict__ RHh,ushort* __restrict__ RHl,
             float* __restrict__ Hf,
             ushort* __restrict__ HXph,ushort* __restrict__ HXpl)
{
  constexpr int MT = BM/32, NT = BN/32;
  constexpr int NSEG = BN/16;     // 1024B segments per plane per tile
  constexpr int SEGW = NSEG/2;    // segments per wave (2 planes / 4 waves)
  __shared__ ushort As[2][2][BM*32];
  __shared__ ushort Bs[2][2][BN*32];

  int bxi = blockIdx.x, byi = blockIdx.y;
  if (swz){
    int id  = byi*gridDim.x + bxi;
    int mch = gridDim.y >> 3;
    int xcd = id & 7, j = id >> 3;
    byi = xcd*mch + j % mch;
    bxi = j / mch;
  }
  const int tid  = threadIdx.x;
  const int lane = tid & 63;
  const int wid  = tid >> 6;
  const int quad = lane >> 4, l15 = lane & 15;
  const int wm = (wid>>1)*(BM/2), wn = (wid&1)*(BN/2);
  const int bm = byi*BM, bn = bxi*BN;

  constexpr int TPR = 256/BM, CPT = 32/TPR;   // A elements per thread per k-step
  const int ar = tid / TPR;
  const int ak = (tid % TPR) * CPT;
  const int grA = bm + ar;
  const int aswz = (ar>>1)&3;

  // per-lane precomputed B global pointers (row+chunk fixed per seg; += k0)
  const ushort* bptr[SEGW];
#pragma unroll
  for (int i=0;i<SEGW;i++){
    int seg = i*4 + wid;
    int plane = (seg >= NSEG) ? 1 : 0;
    int ss = seg & (NSEG-1);
    int row = ss*16 + (lane>>2);
    int cg = (lane&3) ^ ((row>>1)&3);       // inverse swizzle on SOURCE
    bptr[i] = (plane ? Blg : Bhg) + (size_t)(bn + row)*ldb + cg*8;
  }

  f32x4 acc[MT][NT];
#pragma unroll
  for (int i=0;i<MT;i++)
#pragma unroll
    for (int j=0;j<NT;j++) acc[i][j] = (f32x4){0.f,0.f,0.f,0.f};

  float  avf[ASPLIT ? 1 : CPT];
  short8 avh[ASPLIT ? CPT/8 : 1], avl[ASPLIT ? CPT/8 : 1];

  auto load_A = [&](int k0){
    if constexpr (ASPLIT){
      if (grA < M){
#pragma unroll
        for (int i=0;i<CPT/8;i++){
          avh[i] = *(const short8*)(Aph + (size_t)grA*lda + k0 + ak + i*8);
          avl[i] = *(const short8*)(Apl + (size_t)grA*lda + k0 + ak + i*8);
        }
      } else {
#pragma unroll
        for (int i=0;i<CPT/8;i++){
#pragma unroll
          for (int q=0;q<8;q++){ avh[i][q]=0; avl[i][q]=0; }
        }
      }
    } else {
      if (grA < M && ((lda&3)==0) && k0 + ak + CPT <= K) {
        const float* p = Af + (size_t)grA*lda + k0 + ak;
#pragma unroll
        for (int i=0;i<CPT/4;i++) ((float4*)avf)[i] = ((const float4*)p)[i];
      } else {
#pragma unroll
        for (int i=0;i<CPT;i++){
          int gk = k0+ak+i;
          avf[i] = (grA<M && gk<K) ? Af[(size_t)grA*lda+gk] : 0.f;
        }
      }
    }
  };

  auto issue_B = [&](int k0,int buf){
#pragma unroll
    for (int i=0;i<SEGW;i++){
      int seg = i*4 + wid;
      int plane = (seg >= NSEG) ? 1 : 0;
      int ss = seg & (NSEG-1);
      async_ld16(bptr[i] + k0, &Bs[buf][plane][ss*512]);
    }
  };

  auto stage_A = [&](int buf){
    if constexpr (ASPLIT){
#pragma unroll
      for (int i=0;i<CPT/8;i++){
        int pos = (ak/8 + i) ^ aswz;
        *(short8*)&As[buf][0][ar*32 + pos*8] = avh[i];
        *(short8*)&As[buf][1][ar*32 + pos*8] = avl[i];
      }
    } else {
      ushort hs[CPT], ls[CPT];
#pragma unroll
      for (int i=0;i<CPT;i++){
        ushort h = f2bf_rne(avf[i]);
        hs[i]=h; ls[i]=f2bf_rne(avf[i]-bf2f(h));
      }
#pragma unroll
      for (int i=0;i<CPT;i+=8){
        short8 vh, vl;
#pragma unroll
        for (int q=0;q<8;q++){ vh[q]=(short)hs[i+q]; vl[q]=(short)ls[i+q]; }
        int pos = ((ak+i)/8) ^ aswz;
        *(short8*)&As[buf][0][ar*32 + pos*8] = vh;
        *(short8*)&As[buf][1][ar*32 + pos*8] = vl;
      }
    }
  };

  auto compute = [&](int buf){
    short8 afh[MT], afl[MT], bfh[NT], bfl[NT];
#pragma unroll
    for (int i=0;i<MT;i++){
      int row = wm + i*16 + l15;
      int o = row*32 + ((quad ^ ((row>>1)&3))*8);
      afh[i] = *(const short8*)&As[buf][0][o];
      afl[i] = *(const short8*)&As[buf][1][o];
    }
#pragma unroll
    for (int j=0;j<NT;j++){
      int row = wn + j*16 + l15;
      int o = row*32 + ((quad ^ ((row>>1)&3))*8);
      bfh[j] = *(const short8*)&Bs[buf][0][o];
      bfl[j] = *(const short8*)&Bs[buf][1][o];
    }
#pragma unroll
    for (int i=0;i<MT;i++)
#pragma unroll
      for (int j=0;j<NT;j++)
        acc[i][j] = __builtin_amdgcn_mfma_f32_16x16x32_bf16(afh[i], bfh[j], acc[i][j], 0,0,0);
#pragma unroll
    for (int i=0;i<MT;i++)
#pragma unroll
      for (int j=0;j<NT;j++)
        acc[i][j] = __builtin_amdgcn_mfma_f32_16x16x32_bf16(afh[i], bfl[j], acc[i][j], 0,0,0);
#pragma unroll
    for (int i=0;i<MT;i++)
#pragma unroll
      for (int j=0;j<NT;j++)
        acc[i][j] = __builtin_amdgcn_mfma_f32_16x16x32_bf16(afl[i], bfh[j], acc[i][j], 0,0,0);
  };

  // ---- prologue: fill buffer 0 ----
  load_A(0);
  issue_B(0, 0);
  stage_A(0);            // waits A regs (counted vmcnt; B gloads younger)
  __syncthreads();       // drains B(0) — one-time exposed latency

  int cur = 0;
  for (int k0 = 0; k0 < K; k0 += 32){
    if (k0 + 32 < K){
      load_A(k0+32);           // A(k+1) regs in flight
      issue_B(k0+32, cur^1);   // B(k+1) -> back buffer, lands during MFMA
      compute(cur);
      stage_A(cur^1);          // wait A(k+1) (vmcnt ~SEGW, counted), write LDS
    } else {
      compute(cur);
    }
    __syncthreads();           // vmcnt(0): B(k+1) had full MFMA window
    cur ^= 1;
  }

  // ---- epilogue: C/D layout col=lane&15, row=quad*4+reg ----
  if (mode == 0) {
#pragma unroll
    for (int i=0;i<MT;i++){
      int gm0 = bm + wm + i*16 + quad*4;
#pragma unroll
      for (int j=0;j<NT;j++){
        int gn = bn + wn + j*16 + l15;
        if (gn >= N) continue;
#pragma unroll
        for (int r=0;r<4;r++){
          int gm = gm0 + r;
          if (gm >= M) continue;
          float v = acc[i][j][r];
          if (Cin)  v += Cin[(size_t)gm*ldc+gn];
          if (bias) v += bias[gn];
          if (act==1) v = sigmf(v);
          else if (act==2) v = tanhf(v);
          if (Cf){
            Cf[(size_t)gm*ldc+gn] = v;
            if (dupoff) Cf[(size_t)gm*ldc+gn+dupoff] = v;
          }
          if (Cph){
            ushort h_ = f2bf_rne(v);
            ushort l_ = f2bf_rne(v - bf2f(h_));
            size_t p = (size_t)gm*ldcp + gn;
            Cph[p]=h_; Cpl[p]=l_;
            if (dupp){ Cph[p+dupp]=h_; Cpl[p+dupp]=l_; }
          }
        }
      }
    }
  } else if (mode == 1) {   // GATE
#pragma unroll
    for (int i=0;i<MT;i++){
#pragma unroll
      for (int r=0;r<4;r++){
        int gm = bm + wm + i*16 + quad*4 + r;
        if (gm >= M) continue;
        bool isrel = gm < brt;
        int s=0,o=0; const float* g1row = nullptr;
        if (isrel){ s = rel[gm*3+1]; o = rel[gm*3+2]; }
        else g1row = G1 + (size_t)(gm-brt)*1536;
#pragma unroll
        for (int j=0;j<NT;j++){
          int gn = bn + wn + j*16 + l15;
          float v = acc[i][j][r];
          if (gn < 512){
            float g = isrel ? Gso[(size_t)s*3072+gn] + Gso[(size_t)o*3072+1536+gn]
                            : g1row[gn];
            Zb[(size_t)gm*512+gn] = sigmf(v + g + bias[gn]);
          } else {
            int h = gn - 512;
            float g = isrel ? Gso[(size_t)s*3072+512+h] + Gso[(size_t)o*3072+2048+h]
                            : g1row[512+h];
            float rhv = sigmf(v + g + bias2[h]) * Hf[(size_t)gm*512+h];
            ushort h_ = f2bf_rne(rhv);
            ushort l_ = f2bf_rne(rhv - bf2f(h_));
            RHh[(size_t)gm*512+h]=h_; RHl[(size_t)gm*512+h]=l_;
          }
        }
      }
    }
  } else {                  // UPD
#pragma unroll
    for (int i=0;i<MT;i++){
#pragma unroll
      for (int r=0;r<4;r++){
        int gm = bm + wm + i*16 + quad*4 + r;
        if (gm >= M) continue;
        bool isrel = gm < brt;
        int s=0,o=0; const float* g1row = nullptr;
        if (isrel){ s = rel[gm*3+1]; o = rel[gm*3+2]; }
        else g1row = G1 + (size_t)(gm-brt)*1536;
#pragma unroll
        for (int j=0;j<NT;j++){
          int h = bn + wn + j*16 + l15;
          float v = acc[i][j][r];
          float g = isrel ? Gso[(size_t)s*3072+1024+h] + Gso[(size_t)o*3072+2560+h]
                          : g1row[1024+h];
          float hh = tanhf(v + g + bias[h]);
          size_t ix = (size_t)gm*512+h;
          float z = Zb[ix];
          float hn = (1.f-z)*Hf[ix] + z*hh;
          Hf[ix] = hn;
          ushort h_ = f2bf_rne(hn);
          ushort l_ = f2bf_rne(hn - bf2f(h_));
          size_t p = (size_t)gm*1024+h;
          HXph[p]=h_; HXpl[p]=l_;
        }
      }
    }
  }
}

// ---------------------------------------------------------------------------
// Transpose+split weight: src fp32 [K][N] -> dh/dl bf16 [rowoff+n][koff+k]
// k in [K, gridDim.x*32) zero-padded; rows n in [N, Npad) zero-filled so
// global_load_lds staging never reads garbage.
// ---------------------------------------------------------------------------
__global__ __launch_bounds__(256)
void tsplit(const float* __restrict__ src,int K,int N,
            ushort* __restrict__ dh, ushort* __restrict__ dl,
            int dld,int rowoff,int koff,int Npad)
{
  __shared__ float t[32][33];
  const int tx = threadIdx.x, ty = threadIdx.y;
  const int kb = blockIdx.x*32, nb = blockIdx.y*32;
#pragma unroll
  for (int r=0;r<4;r++){
    int k = kb + ty + r*8, n = nb + tx;
    t[ty+r*8][tx] = (k<K && n<N) ? src[(size_t)k*N + n] : 0.f;
  }
  __syncthreads();
#pragma unroll
  for (int r=0;r<4;r++){
    int n = nb + ty + r*8, k = kb + tx;
    if (n < Npad){
      float v = t[tx][ty+r*8];
      ushort h = f2bf_rne(v);
      ushort l = f2bf_rne(v - bf2f(h));
      size_t o = (size_t)(rowoff+n)*dld + koff + k;
      dh[o]=h; dl[o]=l;
    }
  }
}

// ---------------------------------------------------------------------------
__global__ __launch_bounds__(64)
void softmax_kernel(const float* __restrict__ in, float* __restrict__ out,
                    int cols, int ldi, int ldo, int padto)
{
  int row = blockIdx.x, lane = threadIdx.x;
  const float* rp = in + (size_t)row*ldi;
  float m = -INFINITY;
  for (int c = lane; c < cols; c += 64) m = fmaxf(m, rp[c]);
  for (int off = 32; off; off >>= 1) m = fmaxf(m, __shfl_xor(m, off));
  float s = 0.f;
  for (int c = lane; c < cols; c += 64) s += expf(rp[c]-m);
  for (int off = 32; off; off >>= 1) s += __shfl_xor(s, off);
  float inv = 1.f/s;
  float* op = out + (size_t)row*ldo;
  for (int c = lane; c < padto; c += 64)
    op[c] = (c < cols) ? expf(rp[c]-m)*inv : 0.f;
}

__global__ __launch_bounds__(64)
void argmax_kernel(const float* __restrict__ ref, float* __restrict__ preds)
{
  int row = blockIdx.x, lane = threadIdx.x;
  const float* rp = ref + (size_t)row*NOc;
  float bv = -INFINITY; int bi = NOc;
  for (int c = 1+lane; c < NOc; c += 64) { float v = rp[c]; if (v > bv) { bv=v; bi=c; } }
  for (int off=32; off; off>>=1) {
    float ov = __shfl_xor(bv, off); int oi = __shfl_xor(bi, off);
    if (ov > bv || (ov == bv && oi < bi)) { bv = ov; bi = oi; }
  }
  if (lane==0) preds[row] = (float)bi;
}

// segment sums of Hf rel rows (ld 512) into SumSO [512][1024]
__global__ __launch_bounds__(64)
void segsum2(const float* __restrict__ Hf, const int* __restrict__ rel_inds,
             float* __restrict__ SumSO)
{
  __shared__ float accS[64][64];
  __shared__ float accO[64][64];
  const int t = threadIdx.x;
  const int hb = blockIdx.x*64;
  const int img = blockIdx.z;
  const int relbase = img*Rn + blockIdx.y*(Rn/4);
  for (int ob=0; ob<64; ob++){ accS[ob][t]=0.f; accO[ob][t]=0.f; }
  for (int i=0;i<Rn/4;i++){
    int r = relbase+i;
    int s = rel_inds[r*3+1] - img*64;
    int o = rel_inds[r*3+2] - img*64;
    float v = Hf[(size_t)r*512 + hb + t];
    accS[s][t]+=v; accO[o][t]+=v;
  }
  for (int ob=0;ob<64;ob++){
    size_t rowb = (size_t)(img*64+ob)*1024 + hb + t;
    atomicAdd(&SumSO[rowb],     accS[ob][t]);
    atomicAdd(&SumSO[rowb+512], accO[ob][t]);
  }
}

// ---------------------------------------------------------------------------
#define FZ0 0,nullptr,nullptr,nullptr,0,nullptr,nullptr,nullptr,nullptr,nullptr,nullptr

static void TS(hipStream_t s,const float*src,int K,int N,ushort*dh,ushort*dl,
               int dld,int rowoff,int koff,int Kpad,int Npad){
  dim3 g(Kpad/32,(Npad+31)/32);
  tsplit<<<g,dim3(32,8),0,s>>>(src,K,N,dh,dl,dld,rowoff,koff,Npad);
}

extern "C" void kernel_launch(void* const* d_in, const int* in_sizes, int n_in,
                              void* d_out, int out_size, void* d_ws, size_t ws_size,
                              hipStream_t stream) {
  (void)in_sizes; (void)n_in; (void)out_size; (void)ws_size;
  const int*   rel_inds   = (const int*)  d_in[1];
  const float* obj_fmaps  = (const float*)d_in[2];
  const float* obj_logits = (const float*)d_in[3];
  const float* vr         = (const float*)d_in[4];
  const float* W_obj      = (const float*)d_in[5];
  const float* b_obj      = (const float*)d_in[6];
  const float* W_rel      = (const float*)d_in[7];
  const float* b_rel      = (const float*)d_in[8];
  const float* W_prob     = (const float*)d_in[9];
  const float* b_prob     = (const float*)d_in[10];
  const float* W_so       = (const float*)d_in[11];
  const float* W_oo       = (const float*)d_in[12];
  const float* W_rs       = (const float*)d_in[13];
  const float* W_ro       = (const float*)d_in[14];
  const float* Wz         = (const float*)d_in[15];
  const float* Uz         = (const float*)d_in[16];
  const float* bz         = (const float*)d_in[17];
  const float* Wr         = (const float*)d_in[18];
  const float* Ur         = (const float*)d_in[19];
  const float* br         = (const float*)d_in[20];
  const float* Wh         = (const float*)d_in[21];
  const float* Uh         = (const float*)d_in[22];
  const float* bh         = (const float*)d_in[23];
  const float* W_out_rel  = (const float*)d_in[24];
  const float* b_out_rel  = (const float*)d_in[25];
  const float* W_cls_rel  = (const float*)d_in[26];
  const float* b_cls_rel  = (const float*)d_in[27];
  const float* W_out_obj  = (const float*)d_in[28];
  const float* b_out_obj  = (const float*)d_in[29];
  const float* W_cls_obj  = (const float*)d_in[30];
  const float* b_cls_obj  = (const float*)d_in[31];

  // output layout (floats): obj_ref | obj_preds | rel_logits | scpred | scent
  float* out          = (float*)d_out;
  float* out_obj_ref  = out;
  float* out_preds    = out + 77312;
  float* out_rel_log  = out + 77824;
  float* out_scpred   = out + 913408;
  float* out_scent    = out + 1748992;

  // ---- workspace carve ----
  char* base = (char*)d_ws; size_t off = 0;
  auto alloc = [&](size_t bytes)->void*{ void* p = base+off; off = (off+bytes+255)&~(size_t)255; return p; };
  float*  Hf    = (float*) alloc((size_t)Mall*512*4);    // fp32 hidden state (hr / ho)
  ushort* HXph  = (ushort*)alloc((size_t)Mall*1024*2);   // planes: [h | x]
  ushort* HXpl  = (ushort*)alloc((size_t)Mall*1024*2);
  ushort* RHh   = (ushort*)alloc((size_t)Mall*512*2);    // r*h planes; reused as Crel planes
  ushort* RHl   = (ushort*)alloc((size_t)Mall*512*2);
  float*  Zb    = (float*) alloc((size_t)Mall*512*4);    // z gate; setup scratch alias
  ushort* Bt3h  = (ushort*)alloc((size_t)1536*512*2);    // [Wz|Wr|Wh]^T
  ushort* Bt3l  = (ushort*)alloc((size_t)1536*512*2);
  ushort* BtU2h = (ushort*)alloc((size_t)1024*512*2);    // [Uz|Ur]^T
  ushort* BtU2l = (ushort*)alloc((size_t)1024*512*2);
  ushort* BtUHh = (ushort*)alloc((size_t)512*512*2);     // Uh^T
  ushort* BtUHl = (ushort*)alloc((size_t)512*512*2);
  ushort* BtPh  = (ushort*)alloc((size_t)1536*1024*2);   // ([W_rs;W_ro]@cat3)^T
  ushort* BtPl  = (ushort*)alloc((size_t)1536*1024*2);
  ushort* BtORh = (ushort*)alloc((size_t)512*1024*2);    // W_out_rel^T
  ushort* BtORl = (ushort*)alloc((size_t)512*1024*2);
  ushort* BtCRh = (ushort*)alloc((size_t)64*512*2);      // W_cls_rel^T (rows padded to 64)
  ushort* BtCRl = (ushort*)alloc((size_t)64*512*2);
  ushort* BtOOh = (ushort*)alloc((size_t)512*1024*2);    // W_out_obj^T
  ushort* BtOOl = (ushort*)alloc((size_t)512*1024*2);
  ushort* BtCOh = (ushort*)alloc((size_t)192*512*2);     // W_cls_obj^T (rows padded to 192)
  ushort* BtCOl = (ushort*)alloc((size_t)192*512*2);
  ushort* BtWCh = (ushort*)alloc((size_t)3072*512*2);    // [Wso@cat3|Woo@cat3]^T
  ushort* BtWCl = (ushort*)alloc((size_t)3072*512*2);
  float*  Gso   = (float*) alloc((size_t)512*3072*4);
  float*  G1    = (float*) alloc((size_t)512*1536*4);
  float*  SumSO = (float*) alloc((size_t)512*1024*4);
  float*  oprob = (float*) alloc((size_t)512*152*4);
  float*  Xotmp = (float*) alloc((size_t)512*512*4);
  ushort* COph  = (ushort*)alloc((size_t)512*512*2);     // Cobj planes
  ushort* COpl  = (ushort*)alloc((size_t)512*512*2);

  // setup-only aliases inside Zb (34.6 MB; aliases total ~29.7 MB)
  ushort* BtRELh = (ushort*)Zb;                          // W_rel^T [512][4096]
  ushort* BtRELl = BtRELh + (size_t)512*4096;
  ushort* BtOBJh = BtRELl + (size_t)512*4096;            // W_obj^T
  ushort* BtOBJl = BtOBJh + (size_t)512*4096;
  ushort* BtPRh  = BtOBJl + (size_t)512*4096;            // W_prob^T [512][160]
  ushort* BtPRl  = BtPRh  + (size_t)512*160;
  float*  Wcat   = (float*)(BtPRl + (size_t)512*160);    // fp32 [512][3072]
  float*  Pfp    = Wcat + (size_t)512*3072;              // fp32 [1024][1536]

  // ---- setup ----
  softmax_kernel<<<512,64,0,stream>>>(obj_logits, oprob, NOc, NOc, 152, 152);
  TS(stream, W_rel,  4096,512, BtRELh,BtRELl, 4096, 0,0, 4096, 512);
  TS(stream, W_obj,  4096,512, BtOBJh,BtOBJl, 4096, 0,0, 4096, 512);
  TS(stream, W_prob,  151,512, BtPRh, BtPRl,   160, 0,0,  160, 512);
  TS(stream, Wz, 512,512, Bt3h,Bt3l, 512,    0,0, 512, 512);
  TS(stream, Wr, 512,512, Bt3h,Bt3l, 512,  512,0, 512, 512);
  TS(stream, Wh, 512,512, Bt3h,Bt3l, 512, 1024,0, 512, 512);
  TS(stream, Uz, 512,512, BtU2h,BtU2l, 512,   0,0, 512, 512);
  TS(stream, Ur, 512,512, BtU2h,BtU2l, 512, 512,0, 512, 512);
  TS(stream, Uh, 512,512, BtUHh,BtUHl, 512, 0,0, 512, 512);
  TS(stream, W_out_rel, 1024,512, BtORh,BtORl, 1024, 0,0, 1024, 512);
  TS(stream, W_cls_rel,  512, 51, BtCRh,BtCRl,  512, 0,0,  512, 64);
  TS(stream, W_out_obj, 1024,512, BtOOh,BtOOl, 1024, 0,0, 1024, 512);
  TS(stream, W_cls_obj,  512,151, BtCOh,BtCOl,  512, 0,0,  512, 192);

  // xo: Xotmp = obj_fmaps@W_obj + b_obj ; then += oprob@W_prob + b_prob
  //     -> Hf obj rows (ho init) + planes x-cols & dup h-cols
  {
    dim3 g(8,8);
    gemm_b3<64,64,0><<<g,256,0,stream>>>(obj_fmaps,nullptr,nullptr,BtOBJh,BtOBJl,
      Xotmp,nullptr, 512,512,4096, 4096,4096,512, b_obj,nullptr,0,0,
      nullptr,nullptr,0,0, 1, FZ0);
    gemm_b3<64,64,0><<<g,256,0,stream>>>(oprob,nullptr,nullptr,BtPRh,BtPRl,
      Hf+(size_t)BRt*512, Xotmp, 512,512,151, 152,160,512, b_prob,nullptr,0,0,
      HXph+(size_t)BRt*1024+512, HXpl+(size_t)BRt*1024+512, 1024, -512, 1, FZ0);
  }
  // xr: Hf rel rows (hr init) + planes x-cols & dup h-cols
  {
    dim3 g(2,256);
    gemm_b3<64,256,0><<<g,256,0,stream>>>(vr,nullptr,nullptr,BtRELh,BtRELl,
      Hf,nullptr, BRt,512,4096, 4096,4096,512, b_rel,nullptr,0,0,
      HXph+512, HXpl+512, 1024, -512, 1, FZ0);
  }
  // Wcat = [W_so@cat3 | W_oo@cat3]; P = [W_rs@cat3 ; W_ro@cat3]
  {
    dim3 g(24,8);
    gemm_b3<64,64,0><<<g,256,0,stream>>>(W_so,nullptr,nullptr,Bt3h,Bt3l,
      Wcat,nullptr, 512,1536,512, 512,512,3072, nullptr,nullptr,0,0, nullptr,nullptr,0,0, 1, FZ0);
    gemm_b3<64,64,0><<<g,256,0,stream>>>(W_oo,nullptr,nullptr,Bt3h,Bt3l,
      Wcat+1536,nullptr, 512,1536,512, 512,512,3072, nullptr,nullptr,0,0, nullptr,nullptr,0,0, 1, FZ0);
    gemm_b3<64,64,0><<<g,256,0,stream>>>(W_rs,nullptr,nullptr,Bt3h,Bt3l,
      Pfp,nullptr, 512,1536,512, 512,512,1536, nullptr,nullptr,0,0, nullptr,nullptr,0,0, 1, FZ0);
    gemm_b3<64,64,0><<<g,256,0,stream>>>(W_ro,nullptr,nullptr,Bt3h,Bt3l,
      Pfp+(size_t)512*1536,nullptr, 512,1536,512, 512,512,1536, nullptr,nullptr,0,0, nullptr,nullptr,0,0, 1, FZ0);
  }
  TS(stream, Wcat,  512,3072, BtWCh,BtWCl,  512, 0,0,  512, 3072);
  TS(stream, Pfp,  1024,1536, BtPh, BtPl,  1024, 0,0, 1024, 1536);

  // ---- T GGNN steps ----
  for (int t = 0; t < Tt; t++) {
    // Gso = ho @ [Wso@cat3 | Woo@cat3]   (A = obj h-planes)
    {
      dim3 g(48,8);
      gemm_b3<64,64,1><<<g,256,0,stream>>>(nullptr,HXph+(size_t)BRt*1024,HXpl+(size_t)BRt*1024,
        BtWCh,BtWCl, Gso,nullptr, 512,3072,512, 1024,512,3072,
        nullptr,nullptr,0,0, nullptr,nullptr,0,0, 1, FZ0);
    }
    hipMemsetAsync(SumSO, 0, (size_t)512*1024*4, stream);
    segsum2<<<dim3(8,4,8),64,0,stream>>>(Hf, rel_inds, SumSO);
    // G1 = [SumS|SumO] @ ([W_rs;W_ro]@cat3)
    {
      dim3 g(24,8);
      gemm_b3<64,64,0><<<g,256,0,stream>>>(SumSO,nullptr,nullptr,BtPh,BtPl,
        G1,nullptr, 512,1536,1024, 1024,1024,1536,
        nullptr,nullptr,0,0, nullptr,nullptr,0,0, 1, FZ0);
    }
    // GATE: acc = h @ [Uz|Ur] -> Zb, RH planes
    {
      dim3 g(8,136);
      gemm_b3<128,128,1><<<g,256,0,stream>>>(nullptr,HXph,HXpl,BtU2h,BtU2l,
        nullptr,nullptr, Mall,1024,512, 1024,512,0, bz,br,0,0,
        nullptr,nullptr,0,0, 1,
        1, rel_inds, Gso, G1, BRt, Zb, RHh,RHl, Hf, nullptr,nullptr);
    }
    // UPD: acc = (r*h) @ Uh -> Hf + h-planes
    {
      dim3 g(4,136);
      gemm_b3<128,128,1><<<g,256,0,stream>>>(nullptr,RHh,RHl,BtUHh,BtUHl,
        nullptr,nullptr, Mall,512,512, 512,512,0, bh,nullptr,0,0,
        nullptr,nullptr,0,0, 1,
        2, rel_inds, Gso, G1, BRt, Zb, nullptr,nullptr, Hf, HXph,HXpl);
    }
  }

  // ---- heads ----
  // Crel = tanh([hr|xr]@W_out_rel + b) -> planes (reuse RH)
  {
    dim3 g(4,128);
    gemm_b3<128,128,1><<<g,256,0,stream>>>(nullptr,HXph,HXpl,BtORh,BtORl,
      nullptr,nullptr, BRt,512,1024, 1024,1024,0, b_out_rel,nullptr,2,0,
      RHh,RHl,512,0, 1, FZ0);
  }
  {
    dim3 g(1,256);
    gemm_b3<64,64,1><<<g,256,0,stream>>>(nullptr,RHh,RHl,BtCRh,BtCRl,
      out_rel_log,nullptr, BRt,NRc,512, 512,512,NRc, b_cls_rel,nullptr,0,0,
      nullptr,nullptr,0,0, 1, FZ0);
  }
  softmax_kernel<<<BRt,64,0,stream>>>(out_rel_log, out_scpred, NRc, NRc, NRc, NRc);
  // Cobj = tanh([ho|xo]@W_out_obj + b) -> planes
  {
    dim3 g(8,8);
    gemm_b3<64,64,1><<<g,256,0,stream>>>(nullptr,HXph+(size_t)BRt*1024,HXpl+(size_t)BRt*1024,
      BtOOh,BtOOl, nullptr,nullptr, 512,512,1024, 1024,1024,0, b_out_obj,nullptr,2,0,
      COph,COpl,512,0, 1, FZ0);
  }
  {
    dim3 g(3,8);
    gemm_b3<64,64,1><<<g,256,0,stream>>>(nullptr,COph,COpl,BtCOh,BtCOl,
      out_obj_ref,nullptr, 512,NOc,512, 512,512,NOc, b_cls_obj,nullptr,0,0,
      nullptr,nullptr,0,0, 1, FZ0);
  }
  softmax_kernel<<<512,64,0,stream>>>(out_obj_ref, out_scent, NOc, NOc, NOc, NOc);
  argmax_kernel<<<512,64,0,stream>>>(out_obj_ref, out_preds);
}

// Round 2
// 2459.902 us; speedup vs baseline: 1.0139x; 1.0139x over previous
//
#include <hip/hip_runtime.h>
#include <math.h>

// Problem constants
#define Bn   8
#define Nn   64
#define Rn   2048
#define Dn   4096
#define Hn   512
#define NOc  151
#define NRc  51
#define Tt   3
#define BNt  (Bn*Nn)   // 512 objects
#define BRt  (Bn*Rn)   // 16384 relations
#define Mall (BRt+BNt) // 16896 = rel rows + appended obj rows

typedef __attribute__((ext_vector_type(8))) short short8;
typedef __attribute__((ext_vector_type(4))) float f32x4;

__device__ __forceinline__ float sigmf(float x){ return 1.0f/(1.0f+expf(-x)); }

__device__ __forceinline__ ushort f2bf_rne(float x){
  unsigned u = __float_as_uint(x);
  unsigned r = u + 0x7FFFu + ((u>>16)&1u);
  return (ushort)(r>>16);
}
__device__ __forceinline__ float bf2f(ushort h){
  return __uint_as_float(((unsigned)h)<<16);
}

// async global->LDS, 16B per lane; LDS dest = wave-uniform base + lane*16
__device__ __forceinline__ void async_ld16(const ushort* g, ushort* l){
  __builtin_amdgcn_global_load_lds(
      (const __attribute__((address_space(1))) unsigned int*)g,
      (__attribute__((address_space(3))) unsigned int*)l, 16, 0, 0);
}

// counted waitcnt + raw barrier helpers (T4: never drain prefetch to 0 mid-loop)
#define WAITB(N) asm volatile("s_waitcnt vmcnt(" #N ") lgkmcnt(0)" ::: "memory")
#define SB0 __builtin_amdgcn_sched_barrier(0)

// ---------------------------------------------------------------------------
// bf16x3 MFMA GEMM, v3 pipeline:
//  - LDS double-buffered; ONE raw barrier per 32-wide K-step with COUNTED
//    vmcnt: A(k+2) register-prefetch loads stay in flight across the barrier.
//  - A prefetch distance 2 (two named reg banks, 2x-unrolled loop): HBM
//    latency of the A stream gets a full K-step (~1000 cyc) of cover.
//  - B staged via global_load_lds (linear dest, pre-swizzled global source,
//    XOR chunk swizzle c ^= (row>>1)&3); issued at top of iter, drained by
//    the counted wait after a full MFMA phase.
// B pre-split bf16 hi/lo planes [N][ldb], k-padded AND row-padded to BN mult.
// C = Ah*Bh + Ah*Bl + Al*Bh, fp32 accumulate (~fp32 accuracy).
// swz: XCD-aware block swizzle (requires gridDim.y % 8 == 0).
// mode 0: out = act(acc (+Cin) (+bias)) -> fp32 C (dupoff) and/or planes.
// mode 1 (GATE): z=sig(acc_z+g+bz)->Zb ; r*h=sig(acc_r+g+br)*Hf -> RH planes.
// mode 2 (UPD):  hn=(1-z)h+z*tanh(acc+g+bh) -> Hf fp32 + HX h-planes.
// ---------------------------------------------------------------------------
template<int BM,int BN,int ASPLIT>
__global__ __launch_bounds__(256)
void gemm_b3(const float* __restrict__ Af,
             const ushort* __restrict__ Aph, const ushort* __restrict__ Apl,
             const ushort* __restrict__ Bhg, const ushort* __restrict__ Blg,
             float* __restrict__ Cf, const float* __restrict__ Cin,
             int M,int N,int K,int lda,int ldb,int ldc,
             const float* __restrict__ bias, const float* __restrict__ bias2,
             int act,int dupoff,
             ushort* __restrict__ Cph, ushort* __restrict__ Cpl,int ldcp,int dupp,
             int swz,int mode,const int* __restrict__ rel,
             const float* __restrict__ Gso,const float* __restrict__ G1,
             int brt,float* __restrict__ Zb,
             ushort* __restrict__ RHh,ushort* __restrict__ RHl,
             float* __restrict__ Hf,
             ushort* __restrict__ HXph,ushort* __restrict__ HXpl)
{
  constexpr int MT = BM/32, NT = BN/32;
  constexpr int NSEG = BN/16;     // 1024B segments per plane per tile
  constexpr int SEGW = NSEG/2;    // segments per wave (2 planes / 4 waves)
  __shared__ ushort As[2][2][BM*32];
  __shared__ ushort Bs[2][2][BN*32];

  int bxi = blockIdx.x, byi = blockIdx.y;
  if (swz){
    int id  = byi*gridDim.x + bxi;
    int mch = gridDim.y >> 3;
    int xcd = id & 7, j = id >> 3;
    byi = xcd*mch + j % mch;
    bxi = j / mch;
  }
  const int tid  = threadIdx.x;
  const int lane = tid & 63;
  const int wid  = tid >> 6;
  const int quad = lane >> 4, l15 = lane & 15;
  const int wm = (wid>>1)*(BM/2), wn = (wid&1)*(BN/2);
  const int bm = byi*BM, bn = bxi*BN;

  constexpr int TPR = 256/BM, CPT = 32/TPR;   // A elements per thread per k-step
  constexpr int AOUT = CPT/4;                  // A vmem instrs per thread per k-step
  const int ar = tid / TPR;
  const int ak = (tid % TPR) * CPT;
  const int grA = bm + ar;
  const int aswz = (ar>>1)&3;

  // per-lane precomputed B global pointers (row+chunk fixed per seg; += k0)
  const ushort* bptr[SEGW];
#pragma unroll
  for (int i=0;i<SEGW;i++){
    int seg = i*4 + wid;
    int plane = (seg >= NSEG) ? 1 : 0;
    int ss = seg & (NSEG-1);
    int row = ss*16 + (lane>>2);
    int cg = (lane&3) ^ ((row>>1)&3);       // inverse swizzle on SOURCE
    bptr[i] = (plane ? Blg : Bhg) + (size_t)(bn + row)*ldb + cg*8;
  }

  f32x4 acc[MT][NT];
#pragma unroll
  for (int i=0;i<MT;i++)
#pragma unroll
    for (int j=0;j<NT;j++) acc[i][j] = (f32x4){0.f,0.f,0.f,0.f};

  struct ARegs {
    float  f[ASPLIT ? 1 : CPT];
    short8 h[ASPLIT ? CPT/8 : 1];
    short8 l[ASPLIT ? CPT/8 : 1];
  };
  ARegs a0, a1;

  auto load_A = [&](ARegs& a, int k0){
    if constexpr (ASPLIT){
      if (grA < M){           // wave-uniform (M multiple of rows-per-wave)
#pragma unroll
        for (int i=0;i<CPT/8;i++){
          a.h[i] = *(const short8*)(Aph + (size_t)grA*lda + k0 + ak + i*8);
          a.l[i] = *(const short8*)(Apl + (size_t)grA*lda + k0 + ak + i*8);
        }
      } else {
#pragma unroll
        for (int i=0;i<CPT/8;i++){
#pragma unroll
          for (int q=0;q<8;q++){ a.h[i][q]=0; a.l[i][q]=0; }
        }
      }
    } else {
      // vector-path condition made WAVE-UNIFORM (k0+32<=K) so per-wave
      // vmem instruction counts are deterministic for the counted waits.
      if (grA < M && ((lda&3)==0) && k0 + 32 <= K) {
        const float* p = Af + (size_t)grA*lda + k0 + ak;
#pragma unroll
        for (int i=0;i<CPT/4;i++) ((float4*)a.f)[i] = ((const float4*)p)[i];
      } else {
#pragma unroll
        for (int i=0;i<CPT;i++){
          int gk = k0+ak+i;
          a.f[i] = (grA<M && gk<K) ? Af[(size_t)grA*lda+gk] : 0.f;
        }
      }
    }
  };

  auto issue_B = [&](int k0,int buf){
#pragma unroll
    for (int i=0;i<SEGW;i++){
      int seg = i*4 + wid;
      int plane = (seg >= NSEG) ? 1 : 0;
      int ss = seg & (NSEG-1);
      async_ld16(bptr[i] + k0, &Bs[buf][plane][ss*512]);
    }
  };

  auto stage_A = [&](ARegs& a, int buf){
    if constexpr (ASPLIT){
#pragma unroll
      for (int i=0;i<CPT/8;i++){
        int pos = (ak/8 + i) ^ aswz;
        *(short8*)&As[buf][0][ar*32 + pos*8] = a.h[i];
        *(short8*)&As[buf][1][ar*32 + pos*8] = a.l[i];
      }
    } else {
      ushort hs[CPT], ls[CPT];
#pragma unroll
      for (int i=0;i<CPT;i++){
        ushort h = f2bf_rne(a.f[i]);
        hs[i]=h; ls[i]=f2bf_rne(a.f[i]-bf2f(h));
      }
#pragma unroll
      for (int i=0;i<CPT;i+=8){
        short8 vh, vl;
#pragma unroll
        for (int q=0;q<8;q++){ vh[q]=(short)hs[i+q]; vl[q]=(short)ls[i+q]; }
        int pos = ((ak+i)/8) ^ aswz;
        *(short8*)&As[buf][0][ar*32 + pos*8] = vh;
        *(short8*)&As[buf][1][ar*32 + pos*8] = vl;
      }
    }
  };

  auto compute = [&](int buf){
    short8 afh[MT], afl[MT], bfh[NT], bfl[NT];
#pragma unroll
    for (int i=0;i<MT;i++){
      int row = wm + i*16 + l15;
      int o = row*32 + ((quad ^ ((row>>1)&3))*8);
      afh[i] = *(const short8*)&As[buf][0][o];
      afl[i] = *(const short8*)&As[buf][1][o];
    }
#pragma unroll
    for (int j=0;j<NT;j++){
      int row = wn + j*16 + l15;
      int o = row*32 + ((quad ^ ((row>>1)&3))*8);
      bfh[j] = *(const short8*)&Bs[buf][0][o];
      bfl[j] = *(const short8*)&Bs[buf][1][o];
    }
#pragma unroll
    for (int i=0;i<MT;i++)
#pragma unroll
      for (int j=0;j<NT;j++)
        acc[i][j] = __builtin_amdgcn_mfma_f32_16x16x32_bf16(afh[i], bfh[j], acc[i][j], 0,0,0);
#pragma unroll
    for (int i=0;i<MT;i++)
#pragma unroll
      for (int j=0;j<NT;j++)
        acc[i][j] = __builtin_amdgcn_mfma_f32_16x16x32_bf16(afh[i], bfl[j], acc[i][j], 0,0,0);
#pragma unroll
    for (int i=0;i<MT;i++)
#pragma unroll
      for (int j=0;j<NT;j++)
        acc[i][j] = __builtin_amdgcn_mfma_f32_16x16x32_bf16(afl[i], bfh[j], acc[i][j], 0,0,0);
  };

  // ---- prologue: fill buffer 0; prefetch A(1) into bank a1 ----
  load_A(a0, 0);
  issue_B(0, 0);
  SB0;
  if (32 < K) load_A(a1, 32);
  stage_A(a0, 0);
  if (32 < K) { if constexpr (AOUT==4) WAITB(4); else WAITB(2); }
  else WAITB(0);
  SB0;
  __builtin_amdgcn_s_barrier();
  SB0;

  // ---- main loop: 2x unrolled so reg banks are statically indexed ----
  int k0 = 0, cur = 0;
  while (true) {
    {   // stage from a1, load into a0
      bool h1 = k0+32 < K, h2 = k0+64 < K;
      if (h1) issue_B(k0+32, cur^1);
      SB0;
      if (h2) load_A(a0, k0+64);
      compute(cur);
      if (h1) {
        stage_A(a1, cur^1);
        if (h2) { if constexpr (AOUT==4) WAITB(4); else WAITB(2); }
        else WAITB(0);
        SB0;
        __builtin_amdgcn_s_barrier();
        SB0;
      }
      k0 += 32; cur ^= 1;
      if (!h1) break;
    }
    {   // stage from a0, load into a1
      bool h1 = k0+32 < K, h2 = k0+64 < K;
      if (h1) issue_B(k0+32, cur^1);
      SB0;
      if (h2) load_A(a1, k0+64);
      compute(cur);
      if (h1) {
        stage_A(a0, cur^1);
        if (h2) { if constexpr (AOUT==4) WAITB(4); else WAITB(2); }
        else WAITB(0);
        SB0;
        __builtin_amdgcn_s_barrier();
        SB0;
      }
      k0 += 32; cur ^= 1;
      if (!h1) break;
    }
  }

  // ---- epilogue: C/D layout col=lane&15, row=quad*4+reg ----
  if (mode == 0) {
#pragma unroll
    for (int i=0;i<MT;i++){
      int gm0 = bm + wm + i*16 + quad*4;
#pragma unroll
      for (int j=0;j<NT;j++){
        int gn = bn + wn + j*16 + l15;
        if (gn >= N) continue;
#pragma unroll
        for (int r=0;r<4;r++){
          int gm = gm0 + r;
          if (gm >= M) continue;
          float v = acc[i][j][r];
          if (Cin)  v += Cin[(size_t)gm*ldc+gn];
          if (bias) v += bias[gn];
          if (act==1) v = sigmf(v);
          else if (act==2) v = tanhf(v);
          if (Cf){
            Cf[(size_t)gm*ldc+gn] = v;
            if (dupoff) Cf[(size_t)gm*ldc+gn+dupoff] = v;
          }
          if (Cph){
            ushort h_ = f2bf_rne(v);
            ushort l_ = f2bf_rne(v - bf2f(h_));
            size_t p = (size_t)gm*ldcp + gn;
            Cph[p]=h_; Cpl[p]=l_;
            if (dupp){ Cph[p+dupp]=h_; Cpl[p+dupp]=l_; }
          }
        }
      }
    }
  } else if (mode == 1) {   // GATE
#pragma unroll
    for (int i=0;i<MT;i++){
#pragma unroll
      for (int r=0;r<4;r++){
        int gm = bm + wm + i*16 + quad*4 + r;
        if (gm >= M) continue;
        bool isrel = gm < brt;
        int s=0,o=0; const float* g1row = nullptr;
        if (isrel){ s = rel[gm*3+1]; o = rel[gm*3+2]; }
        else g1row = G1 + (size_t)(gm-brt)*1536;
#pragma unroll
        for (int j=0;j<NT;j++){
          int gn = bn + wn + j*16 + l15;
          float v = acc[i][j][r];
          if (gn < 512){
            float g = isrel ? Gso[(size_t)s*3072+gn] + Gso[(size_t)o*3072+1536+gn]
                            : g1row[gn];
            Zb[(size_t)gm*512+gn] = sigmf(v + g + bias[gn]);
          } else {
            int h = gn - 512;
            float g = isrel ? Gso[(size_t)s*3072+512+h] + Gso[(size_t)o*3072+2048+h]
                            : g1row[512+h];
            float rhv = sigmf(v + g + bias2[h]) * Hf[(size_t)gm*512+h];
            ushort h_ = f2bf_rne(rhv);
            ushort l_ = f2bf_rne(rhv - bf2f(h_));
            RHh[(size_t)gm*512+h]=h_; RHl[(size_t)gm*512+h]=l_;
          }
        }
      }
    }
  } else {                  // UPD
#pragma unroll
    for (int i=0;i<MT;i++){
#pragma unroll
      for (int r=0;r<4;r++){
        int gm = bm + wm + i*16 + quad*4 + r;
        if (gm >= M) continue;
        bool isrel = gm < brt;
        int s=0,o=0; const float* g1row = nullptr;
        if (isrel){ s = rel[gm*3+1]; o = rel[gm*3+2]; }
        else g1row = G1 + (size_t)(gm-brt)*1536;
#pragma unroll
        for (int j=0;j<NT;j++){
          int h = bn + wn + j*16 + l15;
          float v = acc[i][j][r];
          float g = isrel ? Gso[(size_t)s*3072+1024+h] + Gso[(size_t)o*3072+2560+h]
                          : g1row[1024+h];
          float hh = tanhf(v + g + bias[h]);
          size_t ix = (size_t)gm*512+h;
          float z = Zb[ix];
          float hn = (1.f-z)*Hf[ix] + z*hh;
          Hf[ix] = hn;
          ushort h_ = f2bf_rne(hn);
          ushort l_ = f2bf_rne(hn - bf2f(h_));
          size_t p = (size_t)gm*1024+h;
          HXph[p]=h_; HXpl[p]=l_;
        }
      }
    }
  }
}

// ---------------------------------------------------------------------------
// Transpose+split weight: src fp32 [K][N] -> dh/dl bf16 [rowoff+n][koff+k]
// k in [K, gridDim.x*32) zero-padded; rows n in [N, Npad) zero-filled so
// global_load_lds staging never reads garbage.
// ---------------------------------------------------------------------------
__global__ __launch_bounds__(256)
void tsplit(const float* __restrict__ src,int K,int N,
            ushort* __restrict__ dh, ushort* __restrict__ dl,
            int dld,int rowoff,int koff,int Npad)
{
  __shared__ float t[32][33];
  const int tx = threadIdx.x, ty = threadIdx.y;
  const int kb = blockIdx.x*32, nb = blockIdx.y*32;
#pragma unroll
  for (int r=0;r<4;r++){
    int k = kb + ty + r*8, n = nb + tx;
    t[ty+r*8][tx] = (k<K && n<N) ? src[(size_t)k*N + n] : 0.f;
  }
  __syncthreads();
#pragma unroll
  for (int r=0;r<4;r++){
    int n = nb + ty + r*8, k = kb + tx;
    if (n < Npad){
      float v = t[tx][ty+r*8];
      ushort h = f2bf_rne(v);
      ushort l = f2bf_rne(v - bf2f(h));
      size_t o = (size_t)(rowoff+n)*dld + koff + k;
      dh[o]=h; dl[o]=l;
    }
  }
}

// ---------------------------------------------------------------------------
__global__ __launch_bounds__(64)
void softmax_kernel(const float* __restrict__ in, float* __restrict__ out,
                    int cols, int ldi, int ldo, int padto)
{
  int row = blockIdx.x, lane = threadIdx.x;
  const float* rp = in + (size_t)row*ldi;
  float m = -INFINITY;
  for (int c = lane; c < cols; c += 64) m = fmaxf(m, rp[c]);
  for (int off = 32; off; off >>= 1) m = fmaxf(m, __shfl_xor(m, off));
  float s = 0.f;
  for (int c = lane; c < cols; c += 64) s += expf(rp[c]-m);
  for (int off = 32; off; off >>= 1) s += __shfl_xor(s, off);
  float inv = 1.f/s;
  float* op = out + (size_t)row*ldo;
  for (int c = lane; c < padto; c += 64)
    op[c] = (c < cols) ? expf(rp[c]-m)*inv : 0.f;
}

__global__ __launch_bounds__(64)
void argmax_kernel(const float* __restrict__ ref, float* __restrict__ preds)
{
  int row = blockIdx.x, lane = threadIdx.x;
  const float* rp = ref + (size_t)row*NOc;
  float bv = -INFINITY; int bi = NOc;
  for (int c = 1+lane; c < NOc; c += 64) { float v = rp[c]; if (v > bv) { bv=v; bi=c; } }
  for (int off=32; off; off>>=1) {
    float ov = __shfl_xor(bv, off); int oi = __shfl_xor(bi, off);
    if (ov > bv || (ov == bv && oi < bi)) { bv = ov; bi = oi; }
  }
  if (lane==0) preds[row] = (float)bi;
}

// segment sums of Hf rel rows (ld 512) into SumSO [512][1024]
__global__ __launch_bounds__(64)
void segsum2(const float* __restrict__ Hf, const int* __restrict__ rel_inds,
             float* __restrict__ SumSO)
{
  __shared__ float accS[64][64];
  __shared__ float accO[64][64];
  const int t = threadIdx.x;
  const int hb = blockIdx.x*64;
  const int img = blockIdx.z;
  const int relbase = img*Rn + blockIdx.y*(Rn/4);
  for (int ob=0; ob<64; ob++){ accS[ob][t]=0.f; accO[ob][t]=0.f; }
  for (int i=0;i<Rn/4;i++){
    int r = relbase+i;
    int s = rel_inds[r*3+1] - img*64;
    int o = rel_inds[r*3+2] - img*64;
    float v = Hf[(size_t)r*512 + hb + t];
    accS[s][t]+=v; accO[o][t]+=v;
  }
  for (int ob=0;ob<64;ob++){
    size_t rowb = (size_t)(img*64+ob)*1024 + hb + t;
    atomicAdd(&SumSO[rowb],     accS[ob][t]);
    atomicAdd(&SumSO[rowb+512], accO[ob][t]);
  }
}

// ---------------------------------------------------------------------------
#define FZ0 0,nullptr,nullptr,nullptr,0,nullptr,nullptr,nullptr,nullptr,nullptr,nullptr

static void TS(hipStream_t s,const float*src,int K,int N,ushort*dh,ushort*dl,
               int dld,int rowoff,int koff,int Kpad,int Npad){
  dim3 g(Kpad/32,(Npad+31)/32);
  tsplit<<<g,dim3(32,8),0,s>>>(src,K,N,dh,dl,dld,rowoff,koff,Npad);
}

extern "C" void kernel_launch(void* const* d_in, const int* in_sizes, int n_in,
                              void* d_out, int out_size, void* d_ws, size_t ws_size,
                              hipStream_t stream) {
  (void)in_sizes; (void)n_in; (void)out_size; (void)ws_size;
  const int*   rel_inds   = (const int*)  d_in[1];
  const float* obj_fmaps  = (const float*)d_in[2];
  const float* obj_logits = (const float*)d_in[3];
  const float* vr         = (const float*)d_in[4];
  const float* W_obj      = (const float*)d_in[5];
  const float* b_obj      = (const float*)d_in[6];
  const float* W_rel      = (const float*)d_in[7];
  const float* b_rel      = (const float*)d_in[8];
  const float* W_prob     = (const float*)d_in[9];
  const float* b_prob     = (const float*)d_in[10];
  const float* W_so       = (const float*)d_in[11];
  const float* W_oo       = (const float*)d_in[12];
  const float* W_rs       = (const float*)d_in[13];
  const float* W_ro       = (const float*)d_in[14];
  const float* Wz         = (const float*)d_in[15];
  const float* Uz         = (const float*)d_in[16];
  const float* bz         = (const float*)d_in[17];
  const float* Wr         = (const float*)d_in[18];
  const float* Ur         = (const float*)d_in[19];
  const float* br         = (const float*)d_in[20];
  const float* Wh         = (const float*)d_in[21];
  const float* Uh         = (const float*)d_in[22];
  const float* bh         = (const float*)d_in[23];
  const float* W_out_rel  = (const float*)d_in[24];
  const float* b_out_rel  = (const float*)d_in[25];
  const float* W_cls_rel  = (const float*)d_in[26];
  const float* b_cls_rel  = (const float*)d_in[27];
  const float* W_out_obj  = (const float*)d_in[28];
  const float* b_out_obj  = (const float*)d_in[29];
  const float* W_cls_obj  = (const float*)d_in[30];
  const float* b_cls_obj  = (const float*)d_in[31];

  // output layout (floats): obj_ref | obj_preds | rel_logits | scpred | scent
  float* out          = (float*)d_out;
  float* out_obj_ref  = out;
  float* out_preds    = out + 77312;
  float* out_rel_log  = out + 77824;
  float* out_scpred   = out + 913408;
  float* out_scent    = out + 1748992;

  // ---- workspace carve ----
  char* base = (char*)d_ws; size_t off = 0;
  auto alloc = [&](size_t bytes)->void*{ void* p = base+off; off = (off+bytes+255)&~(size_t)255; return p; };
  float*  Hf    = (float*) alloc((size_t)Mall*512*4);    // fp32 hidden state (hr / ho)
  ushort* HXph  = (ushort*)alloc((size_t)Mall*1024*2);   // planes: [h | x]
  ushort* HXpl  = (ushort*)alloc((size_t)Mall*1024*2);
  ushort* RHh   = (ushort*)alloc((size_t)Mall*512*2);    // r*h planes; reused as Crel planes
  ushort* RHl   = (ushort*)alloc((size_t)Mall*512*2);
  float*  Zb    = (float*) alloc((size_t)Mall*512*4);    // z gate; setup scratch alias
  ushort* Bt3h  = (ushort*)alloc((size_t)1536*512*2);    // [Wz|Wr|Wh]^T
  ushort* Bt3l  = (ushort*)alloc((size_t)1536*512*2);
  ushort* BtU2h = (ushort*)alloc((size_t)1024*512*2);    // [Uz|Ur]^T
  ushort* BtU2l = (ushort*)alloc((size_t)1024*512*2);
  ushort* BtUHh = (ushort*)alloc((size_t)512*512*2);     // Uh^T
  ushort* BtUHl = (ushort*)alloc((size_t)512*512*2);
  ushort* BtPh  = (ushort*)alloc((size_t)1536*1024*2);   // ([W_rs;W_ro]@cat3)^T
  ushort* BtPl  = (ushort*)alloc((size_t)1536*1024*2);
  ushort* BtORh = (ushort*)alloc((size_t)512*1024*2);    // W_out_rel^T
  ushort* BtORl = (ushort*)alloc((size_t)512*1024*2);
  ushort* BtCRh = (ushort*)alloc((size_t)64*512*2);      // W_cls_rel^T (rows padded to 64)
  ushort* BtCRl = (ushort*)alloc((size_t)64*512*2);
  ushort* BtOOh = (ushort*)alloc((size_t)512*1024*2);    // W_out_obj^T
  ushort* BtOOl = (ushort*)alloc((size_t)512*1024*2);
  ushort* BtCOh = (ushort*)alloc((size_t)192*512*2);     // W_cls_obj^T (rows padded to 192)
  ushort* BtCOl = (ushort*)alloc((size_t)192*512*2);
  ushort* BtWCh = (ushort*)alloc((size_t)3072*512*2);    // [Wso@cat3|Woo@cat3]^T
  ushort* BtWCl = (ushort*)alloc((size_t)3072*512*2);
  float*  Gso   = (float*) alloc((size_t)512*3072*4);
  float*  G1    = (float*) alloc((size_t)512*1536*4);
  float*  SumSO = (float*) alloc((size_t)512*1024*4);
  float*  oprob = (float*) alloc((size_t)512*152*4);
  float*  Xotmp = (float*) alloc((size_t)512*512*4);
  ushort* COph  = (ushort*)alloc((size_t)512*512*2);     // Cobj planes
  ushort* COpl  = (ushort*)alloc((size_t)512*512*2);

  // setup-only aliases inside Zb (34.6 MB; aliases total ~29.7 MB)
  ushort* BtRELh = (ushort*)Zb;                          // W_rel^T [512][4096]
  ushort* BtRELl = BtRELh + (size_t)512*4096;
  ushort* BtOBJh = BtRELl + (size_t)512*4096;            // W_obj^T
  ushort* BtOBJl = BtOBJh + (size_t)512*4096;
  ushort* BtPRh  = BtOBJl + (size_t)512*4096;            // W_prob^T [512][160]
  ushort* BtPRl  = BtPRh  + (size_t)512*160;
  float*  Wcat   = (float*)(BtPRl + (size_t)512*160);    // fp32 [512][3072]
  float*  Pfp    = Wcat + (size_t)512*3072;              // fp32 [1024][1536]

  // ---- setup ----
  softmax_kernel<<<512,64,0,stream>>>(obj_logits, oprob, NOc, NOc, 152, 152);
  TS(stream, W_rel,  4096,512, BtRELh,BtRELl, 4096, 0,0, 4096, 512);
  TS(stream, W_obj,  4096,512, BtOBJh,BtOBJl, 4096, 0,0, 4096, 512);
  TS(stream, W_prob,  151,512, BtPRh, BtPRl,   160, 0,0,  160, 512);
  TS(stream, Wz, 512,512, Bt3h,Bt3l, 512,    0,0, 512, 512);
  TS(stream, Wr, 512,512, Bt3h,Bt3l, 512,  512,0, 512, 512);
  TS(stream, Wh, 512,512, Bt3h,Bt3l, 512, 1024,0, 512, 512);
  TS(stream, Uz, 512,512, BtU2h,BtU2l, 512,   0,0, 512, 512);
  TS(stream, Ur, 512,512, BtU2h,BtU2l, 512, 512,0, 512, 512);
  TS(stream, Uh, 512,512, BtUHh,BtUHl, 512, 0,0, 512, 512);
  TS(stream, W_out_rel, 1024,512, BtORh,BtORl, 1024, 0,0, 1024, 512);
  TS(stream, W_cls_rel,  512, 51, BtCRh,BtCRl,  512, 0,0,  512, 64);
  TS(stream, W_out_obj, 1024,512, BtOOh,BtOOl, 1024, 0,0, 1024, 512);
  TS(stream, W_cls_obj,  512,151, BtCOh,BtCOl,  512, 0,0,  512, 192);

  // xo: Xotmp = obj_fmaps@W_obj + b_obj ; then += oprob@W_prob + b_prob
  //     -> Hf obj rows (ho init) + planes x-cols & dup h-cols
  {
    dim3 g(8,8);
    gemm_b3<64,64,0><<<g,256,0,stream>>>(obj_fmaps,nullptr,nullptr,BtOBJh,BtOBJl,
      Xotmp,nullptr, 512,512,4096, 4096,4096,512, b_obj,nullptr,0,0,
      nullptr,nullptr,0,0, 1, FZ0);
    gemm_b3<64,64,0><<<g,256,0,stream>>>(oprob,nullptr,nullptr,BtPRh,BtPRl,
      Hf+(size_t)BRt*512, Xotmp, 512,512,151, 152,160,512, b_prob,nullptr,0,0,
      HXph+(size_t)BRt*1024+512, HXpl+(size_t)BRt*1024+512, 1024, -512, 1, FZ0);
  }
  // xr: Hf rel rows (hr init) + planes x-cols & dup h-cols
  {
    dim3 g(2,256);
    gemm_b3<64,256,0><<<g,256,0,stream>>>(vr,nullptr,nullptr,BtRELh,BtRELl,
      Hf,nullptr, BRt,512,4096, 4096,4096,512, b_rel,nullptr,0,0,
      HXph+512, HXpl+512, 1024, -512, 1, FZ0);
  }
  // Wcat = [W_so@cat3 | W_oo@cat3]; P = [W_rs@cat3 ; W_ro@cat3]
  {
    dim3 g(24,8);
    gemm_b3<64,64,0><<<g,256,0,stream>>>(W_so,nullptr,nullptr,Bt3h,Bt3l,
      Wcat,nullptr, 512,1536,512, 512,512,3072, nullptr,nullptr,0,0, nullptr,nullptr,0,0, 1, FZ0);
    gemm_b3<64,64,0><<<g,256,0,stream>>>(W_oo,nullptr,nullptr,Bt3h,Bt3l,
      Wcat+1536,nullptr, 512,1536,512, 512,512,3072, nullptr,nullptr,0,0, nullptr,nullptr,0,0, 1, FZ0);
    gemm_b3<64,64,0><<<g,256,0,stream>>>(W_rs,nullptr,nullptr,Bt3h,Bt3l,
      Pfp,nullptr, 512,1536,512, 512,512,1536, nullptr,nullptr,0,0, nullptr,nullptr,0,0, 1, FZ0);
    gemm_b3<64,64,0><<<g,256,0,stream>>>(W_ro,nullptr,nullptr,Bt3h,Bt3l,
      Pfp+(size_t)512*1536,nullptr, 512,1536,512, 512,512,1536, nullptr,nullptr,0,0, nullptr,nullptr,0,0, 1, FZ0);
  }
  TS(stream, Wcat,  512,3072, BtWCh,BtWCl,  512, 0,0,  512, 3072);
  TS(stream, Pfp,  1024,1536, BtPh, BtPl,  1024, 0,0, 1024, 1536);

  // ---- T GGNN steps ----
  for (int t = 0; t < Tt; t++) {
    // Gso = ho @ [Wso@cat3 | Woo@cat3]   (A = obj h-planes)
    {
      dim3 g(48,8);
      gemm_b3<64,64,1><<<g,256,0,stream>>>(nullptr,HXph+(size_t)BRt*1024,HXpl+(size_t)BRt*1024,
        BtWCh,BtWCl, Gso,nullptr, 512,3072,512, 1024,512,3072,
        nullptr,nullptr,0,0, nullptr,nullptr,0,0, 1, FZ0);
    }
    hipMemsetAsync(SumSO, 0, (size_t)512*1024*4, stream);
    segsum2<<<dim3(8,4,8),64,0,stream>>>(Hf, rel_inds, SumSO);
    // G1 = [SumS|SumO] @ ([W_rs;W_ro]@cat3)
    {
      dim3 g(24,8);
      gemm_b3<64,64,0><<<g,256,0,stream>>>(SumSO,nullptr,nullptr,BtPh,BtPl,
        G1,nullptr, 512,1536,1024, 1024,1024,1536,
        nullptr,nullptr,0,0, nullptr,nullptr,0,0, 1, FZ0);
    }
    // GATE: acc = h @ [Uz|Ur] -> Zb, RH planes
    {
      dim3 g(8,136);
      gemm_b3<128,128,1><<<g,256,0,stream>>>(nullptr,HXph,HXpl,BtU2h,BtU2l,
        nullptr,nullptr, Mall,1024,512, 1024,512,0, bz,br,0,0,
        nullptr,nullptr,0,0, 1,
        1, rel_inds, Gso, G1, BRt, Zb, RHh,RHl, Hf, nullptr,nullptr);
    }
    // UPD: acc = (r*h) @ Uh -> Hf + h-planes
    {
      dim3 g(4,136);
      gemm_b3<128,128,1><<<g,256,0,stream>>>(nullptr,RHh,RHl,BtUHh,BtUHl,
        nullptr,nullptr, Mall,512,512, 512,512,0, bh,nullptr,0,0,
        nullptr,nullptr,0,0, 1,
        2, rel_inds, Gso, G1, BRt, Zb, nullptr,nullptr, Hf, HXph,HXpl);
    }
  }

  // ---- heads ----
  // Crel = tanh([hr|xr]@W_out_rel + b) -> planes (reuse RH)
  {
    dim3 g(4,128);
    gemm_b3<128,128,1><<<g,256,0,stream>>>(nullptr,HXph,HXpl,BtORh,BtORl,
      nullptr,nullptr, BRt,512,1024, 1024,1024,0, b_out_rel,nullptr,2,0,
      RHh,RHl,512,0, 1, FZ0);
  }
  {
    dim3 g(1,256);
    gemm_b3<64,64,1><<<g,256,0,stream>>>(nullptr,RHh,RHl,BtCRh,BtCRl,
      out_rel_log,nullptr, BRt,NRc,512, 512,512,NRc, b_cls_rel,nullptr,0,0,
      nullptr,nullptr,0,0, 1, FZ0);
  }
  softmax_kernel<<<BRt,64,0,stream>>>(out_rel_log, out_scpred, NRc, NRc, NRc, NRc);
  // Cobj = tanh([ho|xo]@W_out_obj + b) -> planes
  {
    dim3 g(8,8);
    gemm_b3<64,64,1><<<g,256,0,stream>>>(nullptr,HXph+(size_t)BRt*1024,HXpl+(size_t)BRt*1024,
      BtOOh,BtOOl, nullptr,nullptr, 512,512,1024, 1024,1024,0, b_out_obj,nullptr,2,0,
      COph,COpl,512,0, 1, FZ0);
  }
  {
    dim3 g(3,8);
    gemm_b3<64,64,1><<<g,256,0,stream>>>(nullptr,COph,COpl,BtCOh,BtCOl,
      out_obj_ref,nullptr, 512,NOc,512, 512,512,NOc, b_cls_obj,nullptr,0,0,
      nullptr,nullptr,0,0, 1, FZ0);
  }
  softmax_kernel<<<512,64,0,stream>>>(out_obj_ref, out_scent, NOc, NOc, NOc, NOc);
  argmax_kernel<<<512,64,0,stream>>>(out_obj_ref, out_preds);
}